// Round 12
// baseline (17936.604 us; speedup 1.0000x reference)
//
#include <hip/hip_runtime.h>
#include <math.h>

#define Bq   16
#define Tq   1024
#define OUTq 64
#define Hq   512
#define Nq   128
#define Mq   40
#define NT   512
#define NISL 16
#define GWG  13        // symmetric WGs per island; island == batch
#define NWG  208
#define EPSq 1e-8f

typedef unsigned long long ull;

__device__ __forceinline__ float sigmf(float x){ return 1.f/(1.f + expf(-x)); }
__device__ __forceinline__ float softplusf(float x){ return (x > 20.f) ? x : log1pf(expf(x)); }

// Agent-scope (IC) tagged words: (tag<<32)|float in ONE atomic 8B word.
// The ONLY cross-WG fabric (L2-local path abandoned: R9-R11 proved it never
// delivers — stale clean lines are never invalidated across producers).
__device__ __forceinline__ ull icld64(const ull* p){
  return __hip_atomic_load(p, __ATOMIC_RELAXED, __HIP_MEMORY_SCOPE_AGENT);
}
__device__ __forceinline__ void icst64(ull* p, ull v){
  __hip_atomic_store(p, v, __ATOMIC_RELAXED, __HIP_MEMORY_SCOPE_AGENT);
}
__device__ __forceinline__ ull packtv(unsigned tag, float v){
  return ((ull)tag << 32) | (ull)__float_as_uint(v);
}
__device__ __forceinline__ float lowf(ull v){ return __uint_as_float((unsigned)v); }
__device__ __forceinline__ float waitw(const ull* p, unsigned want){
  for (;;){
    const ull v = icld64(p);
    if ((unsigned)(v >> 32) == want) return lowf(v);
    __builtin_amdgcn_s_sleep(1);
  }
}

extern "C" __global__ void __launch_bounds__(NT, 1)
ntm_kernel(const float* __restrict__ xg,  const float* __restrict__ h0g,
           const float* __restrict__ c0g, const float* __restrict__ mem0g,
           const float* __restrict__ read0g,
           const float* __restrict__ Wih, const float* __restrict__ bih,
           const float* __restrict__ Whh, const float* __restrict__ bhh,
           const float* __restrict__ Wfc, const float* __restrict__ bfc,
           const float* __restrict__ We,  const float* __restrict__ be,
           const float* __restrict__ Wa,  const float* __restrict__ ba,
           const float* __restrict__ Wk,  const float* __restrict__ bk,
           const float* __restrict__ Wb,  const float* __restrict__ bbeta,
           float* __restrict__ yout, ull* __restrict__ h_tag,
           ull* __restrict__ p_tag)
{
  const int blk = blockIdx.x;
  const int tid = threadIdx.x;
  const int bat  = blk / GWG;          // island == batch
  const int slot = blk - bat*GWG;      // 0..12

  __shared__ __align__(16) float smem[26724];
  float* inp_s  = smem;                // 640: x[0,64) h[64,576)
  float* red_s  = smem + 640;          // 160 x 17
  float* rw_s   = smem + 3360;         // 160 x 41  (r-slice of W_ih)
  float* hw_s   = smem + 9920;         // 121 x 41  (head W, own k-slice)
  float* wfc_s  = smem + 14884;        // 5 x 512   (own out-cols)
  float* M_s    = smem + 17444;        // 128 x 44  (replicated memory)
  float* psum_s = smem + 23076;        // 128 x 14  (gathered head partials)
  float* pred_s = smem + 24868;        // 128 x 5   (own-slice partial chunks)
  float* gate_s = smem + 25508;        // 160
  float* bias_s = smem + 25668;        // 160
  float* c_s    = smem + 25828;        // 40
  float* hh_s   = smem + 25868;        // 40 (own new h slice)
  float* r_s    = smem + 25908;        // 40 (LOCAL r — no hop!)
  float* key_s  = smem + 25948;        // 40
  float* e_s    = smem + 25988;        // 40
  float* a_s    = smem + 26028;        // 40
  float* w_s    = smem + 26068;        // 128
  float* rnv_s  = smem + 26196;        // 128 (row inv-norms, hoisted)
  float* rred_s = smem + 26324;        // 40 x 9
  float* ored_s = smem + 26684;        // 5 x 8

  const int nd    = (slot < 12) ? 40 : 32;
  const int d0    = slot * 40;
  const int rowsR = 4 * nd;
  const int cs    = nd >> 2;           // head-chunk size (10 or 8)
  const int oc0   = slot * 5;
  const int noc   = (slot < 12) ? 5 : 4;   // 12*5+4 = 64 out cols
  const int kseg  = tid & 15;
  const int rslot = tid >> 4;

  // ---- persistent gate weights: 5 padded rows x 36 k ----
  float4 w4[5][9];
  #pragma unroll
  for (int rr = 0; rr < 5; ++rr){
    const int row = rslot*5 + rr;
    if (row < rowsR){
      const int gate = row / nd, ld = row - gate*nd;
      const int grow = gate*Hq + d0 + ld;
      #pragma unroll
      for (int kk = 0; kk < 9; ++kk){
        float v[4];
        #pragma unroll
        for (int c4 = 0; c4 < 4; ++c4){
          const int k = kseg*36 + kk*4 + c4;
          v[c4] = (k < 64) ? Wih[grow*104 + k] : Whh[grow*512 + (k - 64)];
        }
        w4[rr][kk] = make_float4(v[0], v[1], v[2], v[3]);
      }
    } else {
      #pragma unroll
      for (int kk = 0; kk < 9; ++kk) w4[rr][kk] = make_float4(0.f,0.f,0.f,0.f);
    }
  }
  if (tid < rowsR){
    const int gate = tid / nd, ld = tid - gate*nd;
    const int grow = gate*Hq + d0 + ld;
    bias_s[tid] = bih[grow] + bhh[grow];
  }
  for (int i = tid; i < rowsR*40; i += NT){
    const int row = i / 40, m = i - row*40;
    const int gate = row / nd, ld = row - gate*nd;
    rw_s[row*41 + m] = Wih[(gate*Hq + d0 + ld)*104 + 64 + m];
  }
  { // head weights, own k-slice
    const int o = tid & 127, ck = tid >> 7;
    if (o < 121){
      const float* wrow = (o < 40) ? (Wk + o*Hq)
                        : (o < 80) ? (We + (o-40)*Hq)
                        : (o < 120) ? (Wa + (o-80)*Hq) : Wb;
      for (int q = 0; q < cs; ++q)
        hw_s[o*41 + ck*cs + q] = wrow[d0 + ck*cs + q];
    }
  }
  for (int i = tid; i < noc*512; i += NT)
    wfc_s[i] = Wfc[(oc0 + (i >> 9))*Hq + (i & 511)];
  const float bfcv2 = (tid < noc) ? bfc[oc0 + tid] : 0.f;
  #pragma unroll
  for (int q = 0; q < 10; ++q){
    const int e = q*512 + tid;
    const int n = e / 40, m = e - n*40;
    M_s[n*44 + m] = mem0g[bat*(Nq*Mq) + e];
  }
  float hb0 = 0.f, hb1 = 0.f;
  if (tid < 64){
    hb0 = (tid < 40) ? bk[tid] : be[tid-40];
    const int o1 = tid + 64;
    hb1 = (o1 < 80) ? be[o1-40] : (o1 < 120) ? ba[o1-80]
        : (o1 == 120) ? bbeta[0] : 0.f;
  }
  if (tid < nd) c_s[tid] = c0g[bat*Hq + d0 + tid];
  if (tid < 40) r_s[tid] = read0g[bat*Mq + tid];
  if (tid < 16)
    *(float4*)&inp_s[tid*4] = ((const float4*)xg)[(bat*Tq + 0)*16 + tid];
  if (tid < 128)
    *(float4*)&inp_s[64 + tid*4] = ((const float4*)h0g)[bat*128 + tid];
  if (tid < 98){ // zero psum pad rows 121..127 (keep unused lanes NaN-free)
    const int rr2 = 121 + tid/14, cc = tid - (tid/14)*14;
    psum_s[rr2*14 + cc] = 0.f;
  }
  __syncthreads();
  if (tid < 128){ // initial row inv-norms
    float qq = 0.f;
    const float* mrow = &M_s[tid*44];
    #pragma unroll
    for (int q = 0; q < 10; ++q){
      const float4 mv = *(const float4*)&mrow[q*4];
      qq += mv.x*mv.x + mv.y*mv.y + mv.z*mv.z + mv.w*mv.w;
    }
    rnv_s[tid] = 1.f/(sqrtf(qq) + EPSq);
  }
  __syncthreads();

  for (int t = 0; t < Tq; ++t){
    const int p = t & 1;
    const unsigned want = (unsigned)(t + 1);
    // ---- 1) gate GEMV over x(t)|h(t-1) ----
    {
      float acc[5] = {0.f,0.f,0.f,0.f,0.f};
      const float* bp = inp_s + kseg*36;
      #pragma unroll
      for (int kk = 0; kk < 9; ++kk){
        const float4 f = *(const float4*)&bp[kk*4];
        #pragma unroll
        for (int rr = 0; rr < 5; ++rr)
          acc[rr] += w4[rr][kk].x*f.x + w4[rr][kk].y*f.y
                   + w4[rr][kk].z*f.z + w4[rr][kk].w*f.w;
      }
      #pragma unroll
      for (int rr = 0; rr < 5; ++rr)
        red_s[(rslot*5 + rr)*17 + kseg] = acc[rr];
    }
    __syncthreads();                              // S1
    // ---- 2) finalize: k-partials + bias + r-dot (r_s is LOCAL) ----
    if (tid < rowsR){
      float s2 = bias_s[tid];
      const float* rp = &red_s[tid*17];
      #pragma unroll
      for (int q = 0; q < 16; ++q) s2 += rp[q];
      const float* rwp = &rw_s[tid*41];
      #pragma unroll
      for (int m = 0; m < 40; ++m) s2 += rwp[m]*r_s[m];
      gate_s[tid] = s2;
    }
    __syncthreads();                              // S2
    // ---- 3) pointwise + publish own h slice ----
    if (tid < nd){
      const float iv = sigmf(gate_s[tid]);
      const float fv = sigmf(gate_s[nd + tid]);
      const float gv = tanhf(gate_s[2*nd + tid]);
      const float ov = sigmf(gate_s[3*nd + tid]);
      const float cn = fv*c_s[tid] + iv*gv;
      const float hn = ov*tanhf(cn);
      c_s[tid] = cn;
      hh_s[tid] = hn;
      icst64(&h_tag[(ull)(p*NISL + bat)*Hq + d0 + tid], packtv(want, hn));
      if (t == Tq - 1){
        yout[Bq*Tq*OUTq + bat*Hq + d0 + tid] = hn;             // final h
        yout[Bq*Tq*OUTq + Bq*Hq + bat*Hq + d0 + tid] = cn;     // final c
      }
    }
    __syncthreads();                              // S3
    // ---- 4) own-slice head partials (121 outputs x own nd dims) ----
    {
      const int o = tid & 127, ck = tid >> 7;
      if (o < 121){
        float pp = 0.f;
        const float* hwp = &hw_s[o*41 + ck*cs];
        const float* hp  = &hh_s[ck*cs];
        for (int q = 0; q < cs; ++q) pp += hwp[q]*hp[q];
        pred_s[o*5 + ck] = pp;
      }
    }
    __syncthreads();                              // S4
    // ---- 5) publish partials; gather h + partials (THE one hop) ----
    if (tid < 121){
      const float pp = pred_s[tid*5] + pred_s[tid*5+1]
                     + pred_s[tid*5+2] + pred_s[tid*5+3];
      icst64(&p_tag[((ull)(p*NISL + bat)*GWG + slot)*128 + tid],
             packtv(want, pp));
    }
    inp_s[64 + tid] = waitw(&h_tag[(ull)(p*NISL + bat)*Hq + tid], want);
    if (t + 1 < Tq && tid < 16)
      *(float4*)&inp_s[tid*4] = ((const float4*)xg)[(bat*Tq + t + 1)*16 + tid];
    {
      const ull* pb = p_tag + (ull)(p*NISL + bat)*GWG*128;
      #pragma unroll
      for (int base = 0; base < GWG*121; base += NT){
        const int li = base + tid;
        if (li < GWG*121){
          const int w2 = li / 121, o = li - w2*121;
          psum_s[o*14 + w2] = waitw(&pb[w2*128 + o], want);
        }
      }
    }
    __syncthreads();                              // S5
    // ---- 6) wave 0: head sums, activations, softmax (local, redundant) ----
    if (tid < 64){
      const int l = tid;
      float s0 = hb0, s1 = hb1;
      #pragma unroll
      for (int w2 = 0; w2 < 13; ++w2){
        s0 += psum_s[l*14 + w2];
        s1 += psum_s[(l+64)*14 + w2];
      }
      float kv = 0.f;
      if (l < 40){ kv = tanhf(s0); key_s[l] = kv; }
      else       { e_s[l-40] = sigmf(s0); }
      if (l < 16)      e_s[l+24] = sigmf(s1);     // o1 in [64,80)
      else if (l < 56) a_s[l-16] = tanhf(s1);     // o1 in [80,120)
      float bval = softplusf(s1) + EPSq;          // lane 56: o1==120
      const float bet = __shfl(bval, 56);
      float ss = kv*kv;
      #pragma unroll
      for (int off = 32; off; off >>= 1) ss += __shfl_xor(ss, off);
      const float rinv = 1.f/(sqrtf(ss) + EPSq);
      float sc[2];
      #pragma unroll
      for (int half = 0; half < 2; ++half){
        const int n = l + 64*half;
        float dd = 0.f;
        const float* mrow = &M_s[n*44];
        #pragma unroll
        for (int q = 0; q < 10; ++q){
          const float4 mv  = *(const float4*)&mrow[q*4];
          const float4 kvv = *(const float4*)&key_s[q*4];
          dd += mv.x*kvv.x + mv.y*kvv.y + mv.z*kvv.z + mv.w*kvv.w;
        }
        sc[half] = bet * dd * rinv * rnv_s[n];
      }
      float mx = fmaxf(sc[0], sc[1]);
      #pragma unroll
      for (int off = 32; off; off >>= 1) mx = fmaxf(mx, __shfl_xor(mx, off));
      const float e0 = expf(sc[0] - mx), e1 = expf(sc[1] - mx);
      float sm = e0 + e1;
      #pragma unroll
      for (int off = 32; off; off >>= 1) sm += __shfl_xor(sm, off);
      const float inv = 1.f/sm;
      w_s[l] = e0*inv; w_s[l+64] = e1*inv;
    }
    __syncthreads();                              // S6
    // ---- 7) memory update + r partials (local) ; out partials ----
    if (tid < 320){
      const int m = tid % 40, ng = tid / 40;
      const float ev = e_s[m], av = a_s[m];
      float part = 0.f;
      #pragma unroll
      for (int q = 0; q < 16; ++q){
        const int n = ng*16 + q, idx2 = n*44 + m;
        const float mv = M_s[idx2];
        const float wn = w_s[n];
        const float nv = fmaf(wn, fmaf(-ev, mv, av), mv);
        M_s[idx2] = nv;
        part = fmaf(wn, nv, part);
      }
      rred_s[m*9 + ng] = part;
    }
    { // out-column partials over gathered h(t)
      const int wv = tid >> 6, ln = tid & 63;
      const float hval = inp_s[64 + tid];
      for (int c = 0; c < noc; ++c){
        float pc = wfc_s[c*512 + tid] * hval;
        #pragma unroll
        for (int off = 32; off; off >>= 1) pc += __shfl_xor(pc, off);
        if (ln == 0) ored_s[c*8 + wv] = pc;
      }
    }
    __syncthreads();                              // S7
    // ---- 8) r(t) local; row inv-norms for next sim; out store ----
    if (tid < 40){
      float r = 0.f;
      #pragma unroll
      for (int q = 0; q < 8; ++q) r += rred_s[tid*9 + q];
      r_s[tid] = r;
    }
    if (tid < 128){
      float qq = 0.f;
      const float* mrow = &M_s[tid*44];
      #pragma unroll
      for (int q = 0; q < 10; ++q){
        const float4 mv = *(const float4*)&mrow[q*4];
        qq += mv.x*mv.x + mv.y*mv.y + mv.z*mv.z + mv.w*mv.w;
      }
      rnv_s[tid] = 1.f/(sqrtf(qq) + EPSq);
    }
    if (tid < noc){
      float s2 = bfcv2;
      const float* op = &ored_s[tid*8];
      #pragma unroll
      for (int q = 0; q < 8; ++q) s2 += op[q];
      yout[(bat*Tq + t)*OUTq + oc0 + tid] = tanhf(s2);
    }
    __syncthreads();                              // S8
  }
}

extern "C" void kernel_launch(void* const* d_in, const int* in_sizes, int n_in,
                              void* d_out, int out_size, void* d_ws, size_t ws_size,
                              hipStream_t stream){
  const float* xg    = (const float*)d_in[0];
  const float* h0g   = (const float*)d_in[1];
  const float* c0g   = (const float*)d_in[2];
  const float* mem0g = (const float*)d_in[3];
  const float* read0g= (const float*)d_in[4];
  const float* Wih   = (const float*)d_in[5];
  const float* bih   = (const float*)d_in[6];
  const float* Whh   = (const float*)d_in[7];
  const float* bhh   = (const float*)d_in[8];
  const float* Wfc   = (const float*)d_in[9];
  const float* bfc   = (const float*)d_in[10];
  const float* We    = (const float*)d_in[11];
  const float* be    = (const float*)d_in[12];
  const float* Wa    = (const float*)d_in[13];
  const float* ba    = (const float*)d_in[14];
  const float* Wk    = (const float*)d_in[15];
  const float* bk    = (const float*)d_in[16];
  const float* Wb    = (const float*)d_in[17];
  const float* bbeta = (const float*)d_in[18];

  float* yout  = (float*)d_out;
  ull*   h_tag = (ull*)d_ws;                       // 2*16*512 ull = 128 KiB
  ull*   p_tag = (ull*)((char*)d_ws + 131072);     // 2*16*13*128 ull = 416 KiB

  hipMemsetAsync(d_ws, 0, 557056, stream);         // tags=0 != any want (1..1024)
  hipLaunchKernelGGL(ntm_kernel, dim3(NWG), dim3(NT), 0, stream,
                     xg, h0g, c0g, mem0g, read0g, Wih, bih, Whh, bhh,
                     Wfc, bfc, We, be, Wa, ba, Wk, bk, Wb, bbeta,
                     yout, h_tag, p_tag);
}